// Round 6
// baseline (518.488 us; speedup 1.0000x reference)
//
#include <hip/hip_runtime.h>
#include <hip/hip_bf16.h>

typedef _Float16 f16x8 __attribute__((ext_vector_type(8)));
typedef _Float16 f16x4 __attribute__((ext_vector_type(4)));
typedef float f32x4 __attribute__((ext_vector_type(4)));

#define MFMA32(a, b, c) __builtin_amdgcn_mfma_f32_16x16x32_f16(a, b, c, 0, 0, 0)
#define MFMA16(a, b, c) __builtin_amdgcn_mfma_f32_16x16x16f16(a, b, c, 0, 0, 0)

// async global->LDS, 16B per lane, linear dest (wave base + lane*16)
#define GLOAD_LDS16(g, l)                                         \
  __builtin_amdgcn_global_load_lds(                               \
      (const __attribute__((address_space(1))) void*)(g),         \
      (__attribute__((address_space(3))) void*)(l), 16, 0, 0)

// ---------------------------------------------------------------------------
// Kernel 0a: batched transpose + f32->f16 convert.
// ---------------------------------------------------------------------------
__global__ __launch_bounds__(256) void tconv_kernel(
    const float* __restrict__ in, _Float16* __restrict__ out, int R, int C) {
  size_t bat = (size_t)blockIdx.y * R * C;
  int o = blockIdx.x * 256 + threadIdx.x;
  if (o < R * C) {
    int c = o / R, r = o - c * R;
    out[bat + o] = (_Float16)in[bat + (size_t)r * C + c];
  }
}

// ---------------------------------------------------------------------------
// Kernel 0b: straight f32 -> f16 convert, 8 elts/thread.
// ---------------------------------------------------------------------------
__global__ __launch_bounds__(256) void cvt16_kernel(
    const float* __restrict__ in, _Float16* __restrict__ out, int n) {
  int i = (blockIdx.x * 256 + threadIdx.x) * 8;
  if (i < n) {
    float4 a = *(const float4*)(in + i);
    float4 b = *(const float4*)(in + i + 4);
    f16x8 cv;
    cv[0] = (_Float16)a.x; cv[1] = (_Float16)a.y;
    cv[2] = (_Float16)a.z; cv[3] = (_Float16)a.w;
    cv[4] = (_Float16)b.x; cv[5] = (_Float16)b.y;
    cv[6] = (_Float16)b.z; cv[7] = (_Float16)b.w;
    *(f16x8*)(out + i) = cv;
  }
}

// ---------------------------------------------------------------------------
// Kernel 1: fused QKV projection as ONE GEMM.  (REVERTED to the R2 version,
// measured 116.2 us / ~500 TF — three schedule-surgery variants (counted
// 2-phase dbuf, 256^2 4-phase drain, 256^2 counted) all regressed: at K=768
// and this occupancy the TLP of 5 blocks/CU out-hides any source-level
// pipeline, matching m114/m230.)
// C[m][n] = sum_e zh[m][e] * Ut[n][e],  M=16384, N=2304, K=768.
// global_load_lds staging into unpadded [128][64] f16 LDS with XOR swizzle
// (both-sides: pre-swizzled global source + swizzled ds_read).
// Plain x-fastest grid: XCD = x%8 partitions M (A slice 3.1MB, L2-resident).
// ---------------------------------------------------------------------------
__global__ __launch_bounds__(256) void qkv_gemm_kernel(
    const _Float16* __restrict__ zh, const _Float16* __restrict__ Ut,
    _Float16* __restrict__ Qf, _Float16* __restrict__ Kf,
    _Float16* __restrict__ Vt) {
  __shared__ _Float16 As[128 * 64];
  __shared__ _Float16 Bs[128 * 64];

  const int tid = threadIdx.x;
  const int wv = tid >> 6, lane = tid & 63, quad = lane >> 4, l16 = lane & 15;

  const int m0 = blockIdx.x * 128;
  const int by = blockIdx.y;
  const int n0 = by * 128;

  const int srow = lane >> 3;
  const int scol = ((lane & 7) ^ srow) << 3;  // f16 units, inverse swizzle
  const _Float16* Ag = zh + (size_t)(m0 + srow) * 768 + scol;
  const _Float16* Bg = Ut + (size_t)(n0 + srow) * 768 + scol;

  const int cbq = quad * 16;  // byte col of this lane's fragment within row

  f32x4 acc[2][8] = {};

  for (int k0 = 0; k0 < 768; k0 += 64) {
    __syncthreads();
#pragma unroll
    for (int i = 0; i < 4; ++i) {
      const int rb = (i * 4 + wv) * 8;
      GLOAD_LDS16(Ag + (size_t)rb * 768 + k0, (char*)As + rb * 128);
      GLOAD_LDS16(Bg + (size_t)rb * 768 + k0, (char*)Bs + rb * 128);
    }
    __syncthreads();
#pragma unroll
    for (int ks = 0; ks < 2; ++ks) {
      f16x8 af[2], bfr[8];
#pragma unroll
      for (int rt = 0; rt < 2; ++rt) {
        const int r = wv * 32 + rt * 16 + l16;
        af[rt] = *(const f16x8*)((const char*)As + r * 128 +
                                 ((ks * 64 + cbq) ^ ((r & 7) << 4)));
      }
#pragma unroll
      for (int ct = 0; ct < 8; ++ct) {
        const int r = ct * 16 + l16;
        bfr[ct] = *(const f16x8*)((const char*)Bs + r * 128 +
                                  ((ks * 64 + cbq) ^ ((r & 7) << 4)));
      }
#pragma unroll
      for (int rt = 0; rt < 2; ++rt)
#pragma unroll
        for (int ct = 0; ct < 8; ++ct)
          acc[rt][ct] = MFMA32(af[rt], bfr[ct], acc[rt][ct]);
    }
  }

#pragma unroll
  for (int ct = 0; ct < 8; ++ct) {
    const int g = by * 2 + (ct >> 2);
    const int h = g / 3, kk = g - h * 3;
    const int dd = (ct & 3) * 16 + l16;
#pragma unroll
    for (int rt = 0; rt < 2; ++rt) {
#pragma unroll
      for (int r = 0; r < 4; ++r) {
        int m = m0 + wv * 32 + rt * 16 + quad * 4 + r;
        int b = m >> 10, n = m & 1023;
        _Float16 val = (_Float16)acc[rt][ct][r];
        if (kk == 0)
          Qf[(((size_t)h * 16 + b) * 1024 + n) * 64 + dd] = val;
        else if (kk == 1)
          Kf[(((size_t)h * 16 + b) * 1024 + n) * 64 + dd] = val;
        else
          Vt[(((size_t)h * 16 + b) * 64 + dd) * 1024 + n] = val;
      }
    }
  }
}

// ---------------------------------------------------------------------------
// Kernel 2: flash attention per (h,b) — ZERO-LDS / ZERO-BARRIER version.
// Mechanism (m169): K- and V-fragments are wave-invariant (lane-indexed
// only) and each (h,b)'s K/V = 256KB is L2-resident via the XCD-chunked
// grid — LDS staging bought nothing but per-tile barriers and a 36KB LDS
// footprint (4 blocks/CU, 16 waves/CU, everything <30% busy).  Now each
// wave reads its fragments straight from L2 and free-runs with NO sync:
// LDS=0 -> 8 blocks/CU, 32 waves/CU; L2 latency hidden by 8 waves/SIMD.
// Math identical to before: S^T = K.Q^T (swapped operands), exp2 with
// scale folded into Q, lane-resident row sums, P fragments feed PV
// directly from registers.  nt-stores for Of.
// ---------------------------------------------------------------------------
__global__ __launch_bounds__(256) void attn_kernel(
    const _Float16* __restrict__ Qf, const _Float16* __restrict__ Kf,
    const _Float16* __restrict__ Vt, _Float16* __restrict__ Of) {
  const int tid = threadIdx.x;
  const int wv = tid >> 6, lane = tid & 63, quad = lane >> 4, l16 = lane & 15;

  // 1536 blocks = 8 XCD * 192; hb-major chunk keeps an hb's 8 q-blocks on
  // one XCD (K/V = 256KB resident in the 4MB XCD L2).
  const int flat = blockIdx.x;
  const int swz = (flat & 7) * 192 + (flat >> 3);
  const int hb = swz >> 3;
  const int h = hb >> 4, b = hb & 15;
  const _Float16* Q = Qf + (size_t)hb * 65536;
  const _Float16* K = Kf + (size_t)hb * 65536;
  const _Float16* V = Vt + (size_t)hb * 65536;  // [64 dd][1024 n]
  const int q0 = (swz & 7) * 128 + wv * 32;

  // Q fragments (B-operand: n=q=l16, k=d=quad*8+j), scale log2(e)/8 folded
  const _Float16 cs = (_Float16)0.18033688011112042f;
  f16x8 qfr[2][2];
#pragma unroll
  for (int mi = 0; mi < 2; ++mi) {
    const _Float16* qp = Q + (size_t)(q0 + mi * 16 + l16) * 64 + quad * 8;
    qfr[mi][0] = *(const f16x8*)qp * cs;
    qfr[mi][1] = *(const f16x8*)(qp + 32) * cs;
  }

  // per-lane fragment base addresses (lane-invariant across tiles)
  const _Float16* Kfr = K + (size_t)l16 * 64 + quad * 8;    // + ct*16*64 + t*64*64 + ks*32
  const _Float16* Vfr = V + (size_t)l16 * 1024 + quad * 4;  // + dt*16*1024 + t*64 + kb*16

  f32x4 o[2][4] = {};  // O^C: col(l16)=dd within dt, row(quad*4+r)=q
  float lsum[2] = {};  // per-lane row sums, q = l16

  for (int t = 0; t < 16; ++t) {
    // K fragments for this tile: 8 x 16B from L2
    f16x8 kf[4][2];
#pragma unroll
    for (int ct = 0; ct < 4; ++ct)
#pragma unroll
      for (int ks = 0; ks < 2; ++ks)
        kf[ct][ks] =
            *(const f16x8*)(Kfr + (size_t)(t * 64 + ct * 16) * 64 + ks * 32);

    // S^T = K.Q^T
    f32x4 st[2][4] = {};
#pragma unroll
    for (int ct = 0; ct < 4; ++ct)
#pragma unroll
      for (int mi = 0; mi < 2; ++mi) {
        st[mi][ct] = MFMA32(kf[ct][0], qfr[mi][0], st[mi][ct]);
        st[mi][ct] = MFMA32(kf[ct][1], qfr[mi][1], st[mi][ct]);
      }

    // V fragments for this tile: 16 x 8B from L2 (issued before exp so the
    // loads overlap the VALU phase)
    f16x4 vf[4][4];
#pragma unroll
    for (int dt = 0; dt < 4; ++dt)
#pragma unroll
      for (int kb = 0; kb < 4; ++kb)
        vf[dt][kb] =
            *(const f16x4*)(Vfr + (size_t)dt * 16384 + t * 64 + kb * 16);

    // P = exp2(S^T); lane-resident row sums; pack to 16x16x16 A-frags
    f16x4 pa[2][4];
#pragma unroll
    for (int mi = 0; mi < 2; ++mi)
#pragma unroll
      for (int ct = 0; ct < 4; ++ct)
#pragma unroll
        for (int r = 0; r < 4; ++r) {
          float p = __builtin_amdgcn_exp2f(st[mi][ct][r]);
          lsum[mi] += p;
          pa[mi][ct][r] = (_Float16)p;
        }

    // O += P.V
#pragma unroll
    for (int dt = 0; dt < 4; ++dt)
#pragma unroll
      for (int kb = 0; kb < 4; ++kb)
#pragma unroll
        for (int mi = 0; mi < 2; ++mi)
          o[mi][dt] = MFMA16(pa[mi][kb], vf[dt][kb], o[mi][dt]);
  }

  // reduce row sums across quads (each lane holds q=l16 partials)
#pragma unroll
  for (int mi = 0; mi < 2; ++mi) {
    float s = lsum[mi];
    s += __shfl_xor(s, 16, 64);
    s += __shfl_xor(s, 32, 64);
    lsum[mi] = s;
  }

  // Epilogue: O / l, store [b][n][h*64+dd] f16 (nontemporal)
#pragma unroll
  for (int mi = 0; mi < 2; ++mi) {
#pragma unroll
    for (int r = 0; r < 4; ++r) {
      float inv = 1.f / __shfl(lsum[mi], quad * 4 + r, 64);
      int n = q0 + mi * 16 + quad * 4 + r;
#pragma unroll
      for (int dt = 0; dt < 4; ++dt) {
        int dd = dt * 16 + l16;
        __builtin_nontemporal_store(
            (_Float16)(o[mi][dt][r] * inv),
            &Of[((size_t)b * 1024 + n) * 768 + h * 64 + dd]);
      }
    }
  }
}

// ---------------------------------------------------------------------------
// Kernel 3: output projection.  C[m][n] = sum_k Of[m][k] * U_msa[k][n].
// Counted-wait double-buffered 2-phase (kept from R3; it improved ~28us).
// ---------------------------------------------------------------------------
__global__ __launch_bounds__(256) void out_gemm_kernel(
    const _Float16* __restrict__ A, const _Float16* __restrict__ Bt,
    float* __restrict__ Cout) {
  __shared__ _Float16 As[2][128 * 64];
  __shared__ _Float16 Bs[2][128 * 64];

  const int tid = threadIdx.x;
  const int wv = tid >> 6, lane = tid & 63, quad = lane >> 4, l16 = lane & 15;

  const int m0 = blockIdx.x * 128;
  const int n0 = blockIdx.y * 128;

  const int srow = lane >> 3;
  const int scol = ((lane & 7) ^ srow) << 3;
  const _Float16* Ag = A + (size_t)(m0 + srow) * 768 + scol;
  const _Float16* Bg = Bt + (size_t)(n0 + srow) * 768 + scol;

  const int cbq = quad * 16;

  f32x4 acc[2][8] = {};

#pragma unroll
  for (int i = 0; i < 4; ++i) {
    const int rb = (i * 4 + wv) * 8;
    GLOAD_LDS16(Ag + (size_t)rb * 768, (char*)As[0] + rb * 128);
    GLOAD_LDS16(Bg + (size_t)rb * 768, (char*)Bs[0] + rb * 128);
  }
  asm volatile("s_waitcnt vmcnt(0)" ::: "memory");
  __builtin_amdgcn_s_barrier();

  for (int t = 0; t < 12; ++t) {
    const int cur = t & 1;
    if (t < 11) {
      const int k1 = (t + 1) * 64;
#pragma unroll
      for (int i = 0; i < 4; ++i) {
        const int rb = (i * 4 + wv) * 8;
        GLOAD_LDS16(Ag + (size_t)rb * 768 + k1,
                    (char*)As[cur ^ 1] + rb * 128);
        GLOAD_LDS16(Bg + (size_t)rb * 768 + k1,
                    (char*)Bs[cur ^ 1] + rb * 128);
      }
    }
#pragma unroll
    for (int ks = 0; ks < 2; ++ks) {
      f16x8 af[2], bfr[8];
#pragma unroll
      for (int rt = 0; rt < 2; ++rt) {
        const int r = wv * 32 + rt * 16 + l16;
        af[rt] = *(const f16x8*)((const char*)As[cur] + r * 128 +
                                 ((ks * 64 + cbq) ^ ((r & 7) << 4)));
      }
#pragma unroll
      for (int ct = 0; ct < 8; ++ct) {
        const int r = ct * 16 + l16;
        bfr[ct] = *(const f16x8*)((const char*)Bs[cur] + r * 128 +
                                  ((ks * 64 + cbq) ^ ((r & 7) << 4)));
      }
#pragma unroll
      for (int rt = 0; rt < 2; ++rt)
#pragma unroll
        for (int ct = 0; ct < 8; ++ct)
          acc[rt][ct] = MFMA32(af[rt], bfr[ct], acc[rt][ct]);
    }
    if (t < 11) {
      asm volatile("s_waitcnt vmcnt(0)" ::: "memory");
      __builtin_amdgcn_s_barrier();
    }
  }

#pragma unroll
  for (int rt = 0; rt < 2; ++rt) {
#pragma unroll
    for (int ct = 0; ct < 8; ++ct) {
#pragma unroll
      for (int r = 0; r < 4; ++r) {
        int m = m0 + wv * 32 + rt * 16 + quad * 4 + r;
        int n = n0 + ct * 16 + l16;
        __builtin_nontemporal_store(acc[rt][ct][r],
                                    &Cout[(size_t)m * 768 + n]);
      }
    }
  }
}

// ---------------------------------------------------------------------------
// Workspace layout (bytes), total 105,381,888:
//   Ut_qkv @ 0           36*64*768*2    =  3,538,944   ([2304][768] f16)
//   Ut_msa @ 3,538,944   768*768*2      =  1,179,648
//   zh/Of  @ 4,718,592   16384*768*2    = 25,165,824   (aliased)
//   Qf     @ 29,884,416  25,165,824
//   Kf     @ 55,050,240  25,165,824
//   Vt     @ 80,216,064  25,165,824  ([h][b][d][n])
// ---------------------------------------------------------------------------
extern "C" void kernel_launch(void* const* d_in, const int* in_sizes, int n_in,
                              void* d_out, int out_size, void* d_ws,
                              size_t ws_size, hipStream_t stream) {
  const float* z = (const float*)d_in[0];
  const float* Uqkv = (const float*)d_in[1];
  const float* Umsa = (const float*)d_in[2];

  char* ws = (char*)d_ws;
  _Float16* Ut_qkv = (_Float16*)(ws);
  _Float16* Ut_msa = (_Float16*)(ws + 3538944);
  _Float16* zh = (_Float16*)(ws + 4718592);
  _Float16* Of = zh;  // aliased (zh dead before attn writes Of)
  _Float16* Qf = (_Float16*)(ws + 29884416);
  _Float16* Kf = (_Float16*)(ws + 55050240);
  _Float16* Vt = (_Float16*)(ws + 80216064);

  tconv_kernel<<<dim3(192, 36), 256, 0, stream>>>(Uqkv, Ut_qkv, 768, 64);
  tconv_kernel<<<dim3(2304, 1), 256, 0, stream>>>(Umsa, Ut_msa, 768, 768);
  cvt16_kernel<<<dim3(6144, 1), 256, 0, stream>>>(z, zh, 16384 * 768);

  qkv_gemm_kernel<<<dim3(128, 18), 256, 0, stream>>>(zh, Ut_qkv, Qf, Kf, Vt);
  attn_kernel<<<dim3(1536, 1), 256, 0, stream>>>(Qf, Kf, Vt, Of);
  out_gemm_kernel<<<dim3(128, 6), 256, 0, stream>>>(Of, Ut_msa,
                                                    (float*)d_out);
}

// Round 7
// 353.512 us; speedup vs baseline: 1.4667x; 1.4667x over previous
//
#include <hip/hip_runtime.h>
#include <hip/hip_bf16.h>

typedef _Float16 f16x8 __attribute__((ext_vector_type(8)));
typedef _Float16 f16x4 __attribute__((ext_vector_type(4)));
typedef float f32x4 __attribute__((ext_vector_type(4)));

#define MFMA32(a, b, c) __builtin_amdgcn_mfma_f32_16x16x32_f16(a, b, c, 0, 0, 0)
#define MFMA16(a, b, c) __builtin_amdgcn_mfma_f32_16x16x16f16(a, b, c, 0, 0, 0)

// async global->LDS, 16B per lane, linear dest (wave base + lane*16)
#define GLOAD_LDS16(g, l)                                         \
  __builtin_amdgcn_global_load_lds(                               \
      (const __attribute__((address_space(1))) void*)(g),         \
      (__attribute__((address_space(3))) void*)(l), 16, 0, 0)

// ---------------------------------------------------------------------------
// Kernel 0a: batched transpose + f32->f16 convert.
// ---------------------------------------------------------------------------
__global__ __launch_bounds__(256) void tconv_kernel(
    const float* __restrict__ in, _Float16* __restrict__ out, int R, int C) {
  size_t bat = (size_t)blockIdx.y * R * C;
  int o = blockIdx.x * 256 + threadIdx.x;
  if (o < R * C) {
    int c = o / R, r = o - c * R;
    out[bat + o] = (_Float16)in[bat + (size_t)r * C + c];
  }
}

// ---------------------------------------------------------------------------
// Kernel 0b: straight f32 -> f16 convert, 8 elts/thread.
// ---------------------------------------------------------------------------
__global__ __launch_bounds__(256) void cvt16_kernel(
    const float* __restrict__ in, _Float16* __restrict__ out, int n) {
  int i = (blockIdx.x * 256 + threadIdx.x) * 8;
  if (i < n) {
    float4 a = *(const float4*)(in + i);
    float4 b = *(const float4*)(in + i + 4);
    f16x8 cv;
    cv[0] = (_Float16)a.x; cv[1] = (_Float16)a.y;
    cv[2] = (_Float16)a.z; cv[3] = (_Float16)a.w;
    cv[4] = (_Float16)b.x; cv[5] = (_Float16)b.y;
    cv[6] = (_Float16)b.z; cv[7] = (_Float16)b.w;
    *(f16x8*)(out + i) = cv;
  }
}

// ---------------------------------------------------------------------------
// Kernel 1: fused QKV projection as ONE GEMM.  (R2 version — best measured:
// 116.2 us / ~500 TF.  All schedule-surgery variants regressed; at K=768
// the 5-blocks/CU TLP of the simple 2-barrier loop out-hides source-level
// pipelining, matching m114/m230.)
// C[m][n] = sum_e zh[m][e] * Ut[n][e],  M=16384, N=2304, K=768.
// global_load_lds staging into unpadded [128][64] f16 LDS with XOR swizzle
// (both-sides: pre-swizzled global source + swizzled ds_read).
// Plain x-fastest grid: XCD = x%8 partitions M (A slice 3.1MB, L2-resident).
// ---------------------------------------------------------------------------
__global__ __launch_bounds__(256) void qkv_gemm_kernel(
    const _Float16* __restrict__ zh, const _Float16* __restrict__ Ut,
    _Float16* __restrict__ Qf, _Float16* __restrict__ Kf,
    _Float16* __restrict__ Vt) {
  __shared__ _Float16 As[128 * 64];
  __shared__ _Float16 Bs[128 * 64];

  const int tid = threadIdx.x;
  const int wv = tid >> 6, lane = tid & 63, quad = lane >> 4, l16 = lane & 15;

  const int m0 = blockIdx.x * 128;
  const int by = blockIdx.y;
  const int n0 = by * 128;

  const int srow = lane >> 3;
  const int scol = ((lane & 7) ^ srow) << 3;  // f16 units, inverse swizzle
  const _Float16* Ag = zh + (size_t)(m0 + srow) * 768 + scol;
  const _Float16* Bg = Ut + (size_t)(n0 + srow) * 768 + scol;

  const int cbq = quad * 16;  // byte col of this lane's fragment within row

  f32x4 acc[2][8] = {};

  for (int k0 = 0; k0 < 768; k0 += 64) {
    __syncthreads();
#pragma unroll
    for (int i = 0; i < 4; ++i) {
      const int rb = (i * 4 + wv) * 8;
      GLOAD_LDS16(Ag + (size_t)rb * 768 + k0, (char*)As + rb * 128);
      GLOAD_LDS16(Bg + (size_t)rb * 768 + k0, (char*)Bs + rb * 128);
    }
    __syncthreads();
#pragma unroll
    for (int ks = 0; ks < 2; ++ks) {
      f16x8 af[2], bfr[8];
#pragma unroll
      for (int rt = 0; rt < 2; ++rt) {
        const int r = wv * 32 + rt * 16 + l16;
        af[rt] = *(const f16x8*)((const char*)As + r * 128 +
                                 ((ks * 64 + cbq) ^ ((r & 7) << 4)));
      }
#pragma unroll
      for (int ct = 0; ct < 8; ++ct) {
        const int r = ct * 16 + l16;
        bfr[ct] = *(const f16x8*)((const char*)Bs + r * 128 +
                                  ((ks * 64 + cbq) ^ ((r & 7) << 4)));
      }
#pragma unroll
      for (int rt = 0; rt < 2; ++rt)
#pragma unroll
        for (int ct = 0; ct < 8; ++ct)
          acc[rt][ct] = MFMA32(af[rt], bfr[ct], acc[rt][ct]);
    }
  }

#pragma unroll
  for (int ct = 0; ct < 8; ++ct) {
    const int g = by * 2 + (ct >> 2);
    const int h = g / 3, kk = g - h * 3;
    const int dd = (ct & 3) * 16 + l16;
#pragma unroll
    for (int rt = 0; rt < 2; ++rt) {
#pragma unroll
      for (int r = 0; r < 4; ++r) {
        int m = m0 + wv * 32 + rt * 16 + quad * 4 + r;
        int b = m >> 10, n = m & 1023;
        _Float16 val = (_Float16)acc[rt][ct][r];
        if (kk == 0)
          Qf[(((size_t)h * 16 + b) * 1024 + n) * 64 + dd] = val;
        else if (kk == 1)
          Kf[(((size_t)h * 16 + b) * 1024 + n) * 64 + dd] = val;
        else
          Vt[(((size_t)h * 16 + b) * 64 + dd) * 1024 + n] = val;
      }
    }
  }
}

// ---------------------------------------------------------------------------
// Kernel 2: flash attention per (h,b).  (R2 version — best measured ~110us.
// The R6 zero-LDS variant regressed 2.5x: per-wave L2 latency landed on the
// QK->exp->PV chain and K-tile reads were 4x redundant per block.  LDS
// staging amortizes the load once per block and the dbuf/single-barrier
// structure hides it.)
// Block = 128 q rows (4 waves x 32), 16 KV tiles of 64, double-buffered
// K/V LDS (one barrier per tile), setprio(1) around MFMA clusters,
// XCD-chunked 1D grid (FETCH 130->43MB), nt-stores for Of.
// S^T = K.Q^T swapped-operand trick: S^T's C/D layout IS the A-operand
// layout of the 16x16x16 MFMA, so exp2 results feed PV from registers;
// row sums stay lane-resident (q=l16).  scale log2(e)/8 folded into Q.
// ---------------------------------------------------------------------------
__global__ __launch_bounds__(256) void attn_kernel(
    const _Float16* __restrict__ Qf, const _Float16* __restrict__ Kf,
    const _Float16* __restrict__ Vt, _Float16* __restrict__ Of) {
  __shared__ _Float16 Ks[2][64][72];
  __shared__ _Float16 Vs[2][64][72];

  const int tid = threadIdx.x;
  const int wv = tid >> 6, lane = tid & 63, quad = lane >> 4, l16 = lane & 15;

  const int flat = blockIdx.x;
  const int swz = (flat & 7) * 192 + (flat >> 3);
  const int hb = swz >> 3;
  const int h = hb >> 4, b = hb & 15;
  const _Float16* Q = Qf + (size_t)hb * 65536;
  const _Float16* K = Kf + (size_t)hb * 65536;
  const _Float16* V = Vt + (size_t)hb * 65536;  // [64 dd][1024 n]
  const int q0 = (swz & 7) * 128 + wv * 32;

  const _Float16 cs = (_Float16)0.18033688011112042f;
  f16x8 qfr[2][2];
#pragma unroll
  for (int mi = 0; mi < 2; ++mi) {
    const _Float16* qp = Q + (size_t)(q0 + mi * 16 + l16) * 64 + quad * 8;
    qfr[mi][0] = *(const f16x8*)qp * cs;
    qfr[mi][1] = *(const f16x8*)(qp + 32) * cs;
  }

  const int r0 = tid >> 3, c0 = (tid & 7) << 3;
  const _Float16* Kst = K + (size_t)r0 * 64 + c0;
  const _Float16* Vst = V + (size_t)r0 * 1024 + c0;

  uint4 kreg[2], vreg[2];
#pragma unroll
  for (int i = 0; i < 2; ++i) {
    kreg[i] = *(const uint4*)(Kst + i * 2048);
    vreg[i] = *(const uint4*)(Vst + i * 32768);
  }
#pragma unroll
  for (int i = 0; i < 2; ++i) {
    *(uint4*)&Ks[0][r0 + i * 32][c0] = kreg[i];
    *(uint4*)&Vs[0][r0 + i * 32][c0] = vreg[i];
  }
  __syncthreads();

  f32x4 o[2][4] = {};
  float lsum[2] = {};

  for (int t = 0; t < 16; ++t) {
    const int cur = t & 1;
    if (t < 15) {
      int n1 = (t + 1) * 64;
#pragma unroll
      for (int i = 0; i < 2; ++i) {
        kreg[i] = *(const uint4*)(Kst + (size_t)n1 * 64 + i * 2048);
        vreg[i] = *(const uint4*)(Vst + n1 + i * 32768);
      }
    }

    f32x4 st[2][4] = {};
    __builtin_amdgcn_s_setprio(1);
#pragma unroll
    for (int ct = 0; ct < 4; ++ct) {
      f16x8 kf0 = *(const f16x8*)&Ks[cur][ct * 16 + l16][quad * 8];
      f16x8 kf1 = *(const f16x8*)&Ks[cur][ct * 16 + l16][32 + quad * 8];
#pragma unroll
      for (int mi = 0; mi < 2; ++mi) {
        st[mi][ct] = MFMA32(kf0, qfr[mi][0], st[mi][ct]);
        st[mi][ct] = MFMA32(kf1, qfr[mi][1], st[mi][ct]);
      }
    }
    __builtin_amdgcn_s_setprio(0);

    f16x4 pa[2][4];
#pragma unroll
    for (int mi = 0; mi < 2; ++mi)
#pragma unroll
      for (int ct = 0; ct < 4; ++ct)
#pragma unroll
        for (int r = 0; r < 4; ++r) {
          float p = __builtin_amdgcn_exp2f(st[mi][ct][r]);
          lsum[mi] += p;
          pa[mi][ct][r] = (_Float16)p;
        }

    __builtin_amdgcn_s_setprio(1);
#pragma unroll
    for (int dt = 0; dt < 4; ++dt) {
#pragma unroll
      for (int kb = 0; kb < 4; ++kb) {
        f16x4 vf = *(const f16x4*)&Vs[cur][dt * 16 + l16][kb * 16 + quad * 4];
#pragma unroll
        for (int mi = 0; mi < 2; ++mi)
          o[mi][dt] = MFMA16(pa[mi][kb], vf, o[mi][dt]);
      }
    }
    __builtin_amdgcn_s_setprio(0);

    if (t < 15) {
#pragma unroll
      for (int i = 0; i < 2; ++i) {
        *(uint4*)&Ks[cur ^ 1][r0 + i * 32][c0] = kreg[i];
        *(uint4*)&Vs[cur ^ 1][r0 + i * 32][c0] = vreg[i];
      }
      __syncthreads();
    }
  }

#pragma unroll
  for (int mi = 0; mi < 2; ++mi) {
    float s = lsum[mi];
    s += __shfl_xor(s, 16, 64);
    s += __shfl_xor(s, 32, 64);
    lsum[mi] = s;
  }

#pragma unroll
  for (int mi = 0; mi < 2; ++mi) {
#pragma unroll
    for (int r = 0; r < 4; ++r) {
      float inv = 1.f / __shfl(lsum[mi], quad * 4 + r, 64);
      int n = q0 + mi * 16 + quad * 4 + r;
#pragma unroll
      for (int dt = 0; dt < 4; ++dt) {
        int dd = dt * 16 + l16;
        __builtin_nontemporal_store(
            (_Float16)(o[mi][dt][r] * inv),
            &Of[((size_t)b * 1024 + n) * 768 + h * 64 + dd]);
      }
    }
  }
}

// ---------------------------------------------------------------------------
// Kernel 3: output projection.  C[m][n] = sum_k Of[m][k] * U_msa[k][n].
// Counted-wait double-buffered 2-phase (R3 version — improved ~28us vs the
// single-buffer loop; at 6 n-tiles the pipeline fills and out_gemm's short
// K-loop benefits where qkv's didn't).
// ---------------------------------------------------------------------------
__global__ __launch_bounds__(256) void out_gemm_kernel(
    const _Float16* __restrict__ A, const _Float16* __restrict__ Bt,
    float* __restrict__ Cout) {
  __shared__ _Float16 As[2][128 * 64];
  __shared__ _Float16 Bs[2][128 * 64];

  const int tid = threadIdx.x;
  const int wv = tid >> 6, lane = tid & 63, quad = lane >> 4, l16 = lane & 15;

  const int m0 = blockIdx.x * 128;
  const int n0 = blockIdx.y * 128;

  const int srow = lane >> 3;
  const int scol = ((lane & 7) ^ srow) << 3;
  const _Float16* Ag = A + (size_t)(m0 + srow) * 768 + scol;
  const _Float16* Bg = Bt + (size_t)(n0 + srow) * 768 + scol;

  const int cbq = quad * 16;

  f32x4 acc[2][8] = {};

#pragma unroll
  for (int i = 0; i < 4; ++i) {
    const int rb = (i * 4 + wv) * 8;
    GLOAD_LDS16(Ag + (size_t)rb * 768, (char*)As[0] + rb * 128);
    GLOAD_LDS16(Bg + (size_t)rb * 768, (char*)Bs[0] + rb * 128);
  }
  asm volatile("s_waitcnt vmcnt(0)" ::: "memory");
  __builtin_amdgcn_s_barrier();

  for (int t = 0; t < 12; ++t) {
    const int cur = t & 1;
    if (t < 11) {
      const int k1 = (t + 1) * 64;
#pragma unroll
      for (int i = 0; i < 4; ++i) {
        const int rb = (i * 4 + wv) * 8;
        GLOAD_LDS16(Ag + (size_t)rb * 768 + k1,
                    (char*)As[cur ^ 1] + rb * 128);
        GLOAD_LDS16(Bg + (size_t)rb * 768 + k1,
                    (char*)Bs[cur ^ 1] + rb * 128);
      }
    }
#pragma unroll
    for (int ks = 0; ks < 2; ++ks) {
      f16x8 af[2], bfr[8];
#pragma unroll
      for (int rt = 0; rt < 2; ++rt) {
        const int r = wv * 32 + rt * 16 + l16;
        af[rt] = *(const f16x8*)((const char*)As[cur] + r * 128 +
                                 ((ks * 64 + cbq) ^ ((r & 7) << 4)));
      }
#pragma unroll
      for (int ct = 0; ct < 8; ++ct) {
        const int r = ct * 16 + l16;
        bfr[ct] = *(const f16x8*)((const char*)Bs[cur] + r * 128 +
                                  ((ks * 64 + cbq) ^ ((r & 7) << 4)));
      }
#pragma unroll
      for (int rt = 0; rt < 2; ++rt)
#pragma unroll
        for (int ct = 0; ct < 8; ++ct)
          acc[rt][ct] = MFMA32(af[rt], bfr[ct], acc[rt][ct]);
    }
    if (t < 11) {
      asm volatile("s_waitcnt vmcnt(0)" ::: "memory");
      __builtin_amdgcn_s_barrier();
    }
  }

#pragma unroll
  for (int rt = 0; rt < 2; ++rt) {
#pragma unroll
    for (int ct = 0; ct < 8; ++ct) {
#pragma unroll
      for (int r = 0; r < 4; ++r) {
        int m = m0 + wv * 32 + rt * 16 + quad * 4 + r;
        int n = n0 + ct * 16 + l16;
        __builtin_nontemporal_store(acc[rt][ct][r],
                                    &Cout[(size_t)m * 768 + n]);
      }
    }
  }
}

// ---------------------------------------------------------------------------
// Workspace layout (bytes), total 105,381,888:
//   Ut_qkv @ 0           36*64*768*2    =  3,538,944   ([2304][768] f16)
//   Ut_msa @ 3,538,944   768*768*2      =  1,179,648
//   zh/Of  @ 4,718,592   16384*768*2    = 25,165,824   (aliased)
//   Qf     @ 29,884,416  25,165,824
//   Kf     @ 55,050,240  25,165,824
//   Vt     @ 80,216,064  25,165,824  ([h][b][d][n])
// ---------------------------------------------------------------------------
extern "C" void kernel_launch(void* const* d_in, const int* in_sizes, int n_in,
                              void* d_out, int out_size, void* d_ws,
                              size_t ws_size, hipStream_t stream) {
  const float* z = (const float*)d_in[0];
  const float* Uqkv = (const float*)d_in[1];
  const float* Umsa = (const float*)d_in[2];

  char* ws = (char*)d_ws;
  _Float16* Ut_qkv = (_Float16*)(ws);
  _Float16* Ut_msa = (_Float16*)(ws + 3538944);
  _Float16* zh = (_Float16*)(ws + 4718592);
  _Float16* Of = zh;  // aliased (zh dead before attn writes Of)
  _Float16* Qf = (_Float16*)(ws + 29884416);
  _Float16* Kf = (_Float16*)(ws + 55050240);
  _Float16* Vt = (_Float16*)(ws + 80216064);

  tconv_kernel<<<dim3(192, 36), 256, 0, stream>>>(Uqkv, Ut_qkv, 768, 64);
  tconv_kernel<<<dim3(2304, 1), 256, 0, stream>>>(Umsa, Ut_msa, 768, 768);
  cvt16_kernel<<<dim3(6144, 1), 256, 0, stream>>>(z, zh, 16384 * 768);

  qkv_gemm_kernel<<<dim3(128, 18), 256, 0, stream>>>(zh, Ut_qkv, Qf, Kf, Vt);
  attn_kernel<<<dim3(1536, 1), 256, 0, stream>>>(Qf, Kf, Vt, Of);
  out_gemm_kernel<<<dim3(128, 6), 256, 0, stream>>>(Of, Ut_msa,
                                                    (float*)d_out);
}

// Round 8
// 329.175 us; speedup vs baseline: 1.5751x; 1.0739x over previous
//
#include <hip/hip_runtime.h>
#include <hip/hip_bf16.h>

typedef _Float16 f16x8 __attribute__((ext_vector_type(8)));
typedef _Float16 f16x4 __attribute__((ext_vector_type(4)));
typedef float f32x4 __attribute__((ext_vector_type(4)));

#define MFMA32(a, b, c) __builtin_amdgcn_mfma_f32_16x16x32_f16(a, b, c, 0, 0, 0)
#define MFMA16(a, b, c) __builtin_amdgcn_mfma_f32_16x16x16f16(a, b, c, 0, 0, 0)

// async global->LDS, 16B per lane, linear dest (wave base + lane*16)
#define GLOAD_LDS16(g, l)                                         \
  __builtin_amdgcn_global_load_lds(                               \
      (const __attribute__((address_space(1))) void*)(g),         \
      (__attribute__((address_space(3))) void*)(l), 16, 0, 0)

// ---------------------------------------------------------------------------
// Kernel 0: merged preprocessing (was 3 launches: tconv Uqkv, tconv Umsa,
// cvt16 z).  One launch, blockIdx.x-partitioned:
//   wg [0,6144):        z f32 -> zh f16, 8 elts/thread (12,582,912 elts)
//   wg [6144,13056):    Uqkv [36][768][64] -> Ut_qkv [36][64][768] f16
//   wg [13056,15360):   Umsa [768][768]    -> Ut_msa [768][768]^T  f16
// All writes output-coalesced.
// ---------------------------------------------------------------------------
__global__ __launch_bounds__(256) void prep_kernel(
    const float* __restrict__ z, const float* __restrict__ Uqkv,
    const float* __restrict__ Umsa, _Float16* __restrict__ zh,
    _Float16* __restrict__ Ut_qkv, _Float16* __restrict__ Ut_msa) {
  const int wg = blockIdx.x;
  const int tid = threadIdx.x;
  if (wg < 6144) {
    // cvt16: 6144*256*8 = 12,582,912 exact
    const int i = (wg * 256 + tid) * 8;
    float4 a = *(const float4*)(z + i);
    float4 b = *(const float4*)(z + i + 4);
    f16x8 cv;
    cv[0] = (_Float16)a.x; cv[1] = (_Float16)a.y;
    cv[2] = (_Float16)a.z; cv[3] = (_Float16)a.w;
    cv[4] = (_Float16)b.x; cv[5] = (_Float16)b.y;
    cv[6] = (_Float16)b.z; cv[7] = (_Float16)b.w;
    *(f16x8*)(zh + i) = cv;
  } else if (wg < 13056) {
    // Uqkv transpose+convert: 6912*256 = 1,769,472 = 36*49152 exact
    const int idx = (wg - 6144) * 256 + tid;
    const int bat = idx / 49152;         // 768*64 per batch
    const int ob = idx - bat * 49152;    // = c*768 + r  (out [64][768])
    const int c = ob / 768, r = ob - c * 768;
    Ut_qkv[idx] = (_Float16)Uqkv[(size_t)bat * 49152 + r * 64 + c];
  } else {
    // Umsa transpose+convert: 2304*256 = 589,824 = 768*768 exact
    const int idx = (wg - 13056) * 256 + tid;
    const int c = idx / 768, r = idx - c * 768;
    Ut_msa[idx] = (_Float16)Umsa[r * 768 + c];
  }
}

// ---------------------------------------------------------------------------
// Kernel 1: fused QKV projection as ONE GEMM.  (R2 version — best measured:
// ~117 us / ~500 TF, reproduced twice.  All schedule-surgery variants
// regressed; at K=768 the TLP of the simple 2-barrier loop out-hides
// source-level pipelining, matching m114/m230.)
// C[m][n] = sum_e zh[m][e] * Ut[n][e],  M=16384, N=2304, K=768.
// global_load_lds staging into unpadded [128][64] f16 LDS with XOR swizzle
// (both-sides: pre-swizzled global source + swizzled ds_read).
// Plain x-fastest grid: XCD = x%8 partitions M (A slice 3.1MB, L2-resident).
// ---------------------------------------------------------------------------
__global__ __launch_bounds__(256) void qkv_gemm_kernel(
    const _Float16* __restrict__ zh, const _Float16* __restrict__ Ut,
    _Float16* __restrict__ Qf, _Float16* __restrict__ Kf,
    _Float16* __restrict__ Vt) {
  __shared__ _Float16 As[128 * 64];
  __shared__ _Float16 Bs[128 * 64];

  const int tid = threadIdx.x;
  const int wv = tid >> 6, lane = tid & 63, quad = lane >> 4, l16 = lane & 15;

  const int m0 = blockIdx.x * 128;
  const int by = blockIdx.y;
  const int n0 = by * 128;

  const int srow = lane >> 3;
  const int scol = ((lane & 7) ^ srow) << 3;  // f16 units, inverse swizzle
  const _Float16* Ag = zh + (size_t)(m0 + srow) * 768 + scol;
  const _Float16* Bg = Ut + (size_t)(n0 + srow) * 768 + scol;

  const int cbq = quad * 16;  // byte col of this lane's fragment within row

  f32x4 acc[2][8] = {};

  for (int k0 = 0; k0 < 768; k0 += 64) {
    __syncthreads();
#pragma unroll
    for (int i = 0; i < 4; ++i) {
      const int rb = (i * 4 + wv) * 8;
      GLOAD_LDS16(Ag + (size_t)rb * 768 + k0, (char*)As + rb * 128);
      GLOAD_LDS16(Bg + (size_t)rb * 768 + k0, (char*)Bs + rb * 128);
    }
    __syncthreads();
#pragma unroll
    for (int ks = 0; ks < 2; ++ks) {
      f16x8 af[2], bfr[8];
#pragma unroll
      for (int rt = 0; rt < 2; ++rt) {
        const int r = wv * 32 + rt * 16 + l16;
        af[rt] = *(const f16x8*)((const char*)As + r * 128 +
                                 ((ks * 64 + cbq) ^ ((r & 7) << 4)));
      }
#pragma unroll
      for (int ct = 0; ct < 8; ++ct) {
        const int r = ct * 16 + l16;
        bfr[ct] = *(const f16x8*)((const char*)Bs + r * 128 +
                                  ((ks * 64 + cbq) ^ ((r & 7) << 4)));
      }
#pragma unroll
      for (int rt = 0; rt < 2; ++rt)
#pragma unroll
        for (int ct = 0; ct < 8; ++ct)
          acc[rt][ct] = MFMA32(af[rt], bfr[ct], acc[rt][ct]);
    }
  }

#pragma unroll
  for (int ct = 0; ct < 8; ++ct) {
    const int g = by * 2 + (ct >> 2);
    const int h = g / 3, kk = g - h * 3;
    const int dd = (ct & 3) * 16 + l16;
#pragma unroll
    for (int rt = 0; rt < 2; ++rt) {
#pragma unroll
      for (int r = 0; r < 4; ++r) {
        int m = m0 + wv * 32 + rt * 16 + quad * 4 + r;
        int b = m >> 10, n = m & 1023;
        _Float16 val = (_Float16)acc[rt][ct][r];
        if (kk == 0)
          Qf[(((size_t)h * 16 + b) * 1024 + n) * 64 + dd] = val;
        else if (kk == 1)
          Kf[(((size_t)h * 16 + b) * 1024 + n) * 64 + dd] = val;
        else
          Vt[(((size_t)h * 16 + b) * 64 + dd) * 1024 + n] = val;
      }
    }
  }
}

// ---------------------------------------------------------------------------
// Kernel 2: flash attention per (h,b).  (R2 structure; NEW in R8: kb-major
// exp->PV interleave.  Before, all 32 exp2 were gated on the LAST QK MFMA
// and all 32 MFMA16 on the last exp2 — two full serial pipe switches per
// tile.  Now per kb: {exp 8 vals; 8 MFMA16}; exp(kb+1) is independent of
// PV(kb), giving the scheduler an MFMA||VALU ladder (m214 sm-split
// mechanism).  Indexing, LDS layout, sync structure untouched.)
// Block = 128 q rows (4 waves x 32), 16 KV tiles of 64, double-buffered
// K/V LDS (one barrier per tile), setprio on MFMA clusters, XCD-chunked
// 1D grid, nt-stores for Of.  S^T = K.Q^T swapped-operand trick; scale
// log2(e)/8 folded into Q; row sums lane-resident (q=l16).
// ---------------------------------------------------------------------------
__global__ __launch_bounds__(256) void attn_kernel(
    const _Float16* __restrict__ Qf, const _Float16* __restrict__ Kf,
    const _Float16* __restrict__ Vt, _Float16* __restrict__ Of) {
  __shared__ _Float16 Ks[2][64][72];
  __shared__ _Float16 Vs[2][64][72];

  const int tid = threadIdx.x;
  const int wv = tid >> 6, lane = tid & 63, quad = lane >> 4, l16 = lane & 15;

  const int flat = blockIdx.x;
  const int swz = (flat & 7) * 192 + (flat >> 3);
  const int hb = swz >> 3;
  const int h = hb >> 4, b = hb & 15;
  const _Float16* Q = Qf + (size_t)hb * 65536;
  const _Float16* K = Kf + (size_t)hb * 65536;
  const _Float16* V = Vt + (size_t)hb * 65536;  // [64 dd][1024 n]
  const int q0 = (swz & 7) * 128 + wv * 32;

  const _Float16 cs = (_Float16)0.18033688011112042f;
  f16x8 qfr[2][2];
#pragma unroll
  for (int mi = 0; mi < 2; ++mi) {
    const _Float16* qp = Q + (size_t)(q0 + mi * 16 + l16) * 64 + quad * 8;
    qfr[mi][0] = *(const f16x8*)qp * cs;
    qfr[mi][1] = *(const f16x8*)(qp + 32) * cs;
  }

  const int r0 = tid >> 3, c0 = (tid & 7) << 3;
  const _Float16* Kst = K + (size_t)r0 * 64 + c0;
  const _Float16* Vst = V + (size_t)r0 * 1024 + c0;

  uint4 kreg[2], vreg[2];
#pragma unroll
  for (int i = 0; i < 2; ++i) {
    kreg[i] = *(const uint4*)(Kst + i * 2048);
    vreg[i] = *(const uint4*)(Vst + i * 32768);
  }
#pragma unroll
  for (int i = 0; i < 2; ++i) {
    *(uint4*)&Ks[0][r0 + i * 32][c0] = kreg[i];
    *(uint4*)&Vs[0][r0 + i * 32][c0] = vreg[i];
  }
  __syncthreads();

  f32x4 o[2][4] = {};
  float lsum[2] = {};

  for (int t = 0; t < 16; ++t) {
    const int cur = t & 1;
    if (t < 15) {
      int n1 = (t + 1) * 64;
#pragma unroll
      for (int i = 0; i < 2; ++i) {
        kreg[i] = *(const uint4*)(Kst + (size_t)n1 * 64 + i * 2048);
        vreg[i] = *(const uint4*)(Vst + n1 + i * 32768);
      }
    }

    // S^T = K.Q^T
    f32x4 st[2][4] = {};
    __builtin_amdgcn_s_setprio(1);
#pragma unroll
    for (int ct = 0; ct < 4; ++ct) {
      f16x8 kf0 = *(const f16x8*)&Ks[cur][ct * 16 + l16][quad * 8];
      f16x8 kf1 = *(const f16x8*)&Ks[cur][ct * 16 + l16][32 + quad * 8];
#pragma unroll
      for (int mi = 0; mi < 2; ++mi) {
        st[mi][ct] = MFMA32(kf0, qfr[mi][0], st[mi][ct]);
        st[mi][ct] = MFMA32(kf1, qfr[mi][1], st[mi][ct]);
      }
    }
    __builtin_amdgcn_s_setprio(0);

    // kb-major: exp(kb) -> PV(kb); exp(kb+1) overlaps PV(kb)'s MFMAs
#pragma unroll
    for (int kb = 0; kb < 4; ++kb) {
      f16x4 pa[2];
#pragma unroll
      for (int mi = 0; mi < 2; ++mi)
#pragma unroll
        for (int r = 0; r < 4; ++r) {
          float p = __builtin_amdgcn_exp2f(st[mi][kb][r]);
          lsum[mi] += p;
          pa[mi][r] = (_Float16)p;
        }
      __builtin_amdgcn_s_setprio(1);
#pragma unroll
      for (int dt = 0; dt < 4; ++dt) {
        f16x4 vf = *(const f16x4*)&Vs[cur][dt * 16 + l16][kb * 16 + quad * 4];
#pragma unroll
        for (int mi = 0; mi < 2; ++mi)
          o[mi][dt] = MFMA16(pa[mi], vf, o[mi][dt]);
      }
      __builtin_amdgcn_s_setprio(0);
    }

    if (t < 15) {
#pragma unroll
      for (int i = 0; i < 2; ++i) {
        *(uint4*)&Ks[cur ^ 1][r0 + i * 32][c0] = kreg[i];
        *(uint4*)&Vs[cur ^ 1][r0 + i * 32][c0] = vreg[i];
      }
      __syncthreads();
    }
  }

#pragma unroll
  for (int mi = 0; mi < 2; ++mi) {
    float s = lsum[mi];
    s += __shfl_xor(s, 16, 64);
    s += __shfl_xor(s, 32, 64);
    lsum[mi] = s;
  }

#pragma unroll
  for (int mi = 0; mi < 2; ++mi) {
#pragma unroll
    for (int r = 0; r < 4; ++r) {
      float inv = 1.f / __shfl(lsum[mi], quad * 4 + r, 64);
      int n = q0 + mi * 16 + quad * 4 + r;
#pragma unroll
      for (int dt = 0; dt < 4; ++dt) {
        int dd = dt * 16 + l16;
        __builtin_nontemporal_store(
            (_Float16)(o[mi][dt][r] * inv),
            &Of[((size_t)b * 1024 + n) * 768 + h * 64 + dd]);
      }
    }
  }
}

// ---------------------------------------------------------------------------
// Kernel 3: output projection.  C[m][n] = sum_k Of[m][k] * U_msa[k][n].
// Counted-wait double-buffered 2-phase (R3 version — kept).
// ---------------------------------------------------------------------------
__global__ __launch_bounds__(256) void out_gemm_kernel(
    const _Float16* __restrict__ A, const _Float16* __restrict__ Bt,
    float* __restrict__ Cout) {
  __shared__ _Float16 As[2][128 * 64];
  __shared__ _Float16 Bs[2][128 * 64];

  const int tid = threadIdx.x;
  const int wv = tid >> 6, lane = tid & 63, quad = lane >> 4, l16 = lane & 15;

  const int m0 = blockIdx.x * 128;
  const int n0 = blockIdx.y * 128;

  const int srow = lane >> 3;
  const int scol = ((lane & 7) ^ srow) << 3;
  const _Float16* Ag = A + (size_t)(m0 + srow) * 768 + scol;
  const _Float16* Bg = Bt + (size_t)(n0 + srow) * 768 + scol;

  const int cbq = quad * 16;

  f32x4 acc[2][8] = {};

#pragma unroll
  for (int i = 0; i < 4; ++i) {
    const int rb = (i * 4 + wv) * 8;
    GLOAD_LDS16(Ag + (size_t)rb * 768, (char*)As[0] + rb * 128);
    GLOAD_LDS16(Bg + (size_t)rb * 768, (char*)Bs[0] + rb * 128);
  }
  asm volatile("s_waitcnt vmcnt(0)" ::: "memory");
  __builtin_amdgcn_s_barrier();

  for (int t = 0; t < 12; ++t) {
    const int cur = t & 1;
    if (t < 11) {
      const int k1 = (t + 1) * 64;
#pragma unroll
      for (int i = 0; i < 4; ++i) {
        const int rb = (i * 4 + wv) * 8;
        GLOAD_LDS16(Ag + (size_t)rb * 768 + k1,
                    (char*)As[cur ^ 1] + rb * 128);
        GLOAD_LDS16(Bg + (size_t)rb * 768 + k1,
                    (char*)Bs[cur ^ 1] + rb * 128);
      }
    }
#pragma unroll
    for (int ks = 0; ks < 2; ++ks) {
      f16x8 af[2], bfr[8];
#pragma unroll
      for (int rt = 0; rt < 2; ++rt) {
        const int r = wv * 32 + rt * 16 + l16;
        af[rt] = *(const f16x8*)((const char*)As[cur] + r * 128 +
                                 ((ks * 64 + cbq) ^ ((r & 7) << 4)));
      }
#pragma unroll
      for (int ct = 0; ct < 8; ++ct) {
        const int r = ct * 16 + l16;
        bfr[ct] = *(const f16x8*)((const char*)Bs[cur] + r * 128 +
                                  ((ks * 64 + cbq) ^ ((r & 7) << 4)));
      }
#pragma unroll
      for (int rt = 0; rt < 2; ++rt)
#pragma unroll
        for (int ct = 0; ct < 8; ++ct)
          acc[rt][ct] = MFMA32(af[rt], bfr[ct], acc[rt][ct]);
    }
    if (t < 11) {
      asm volatile("s_waitcnt vmcnt(0)" ::: "memory");
      __builtin_amdgcn_s_barrier();
    }
  }

#pragma unroll
  for (int rt = 0; rt < 2; ++rt) {
#pragma unroll
    for (int ct = 0; ct < 8; ++ct) {
#pragma unroll
      for (int r = 0; r < 4; ++r) {
        int m = m0 + wv * 32 + rt * 16 + quad * 4 + r;
        int n = n0 + ct * 16 + l16;
        __builtin_nontemporal_store(acc[rt][ct][r],
                                    &Cout[(size_t)m * 768 + n]);
      }
    }
  }
}

// ---------------------------------------------------------------------------
// Workspace layout (bytes), total 105,381,888:
//   Ut_qkv @ 0           36*64*768*2    =  3,538,944   ([2304][768] f16)
//   Ut_msa @ 3,538,944   768*768*2      =  1,179,648
//   zh/Of  @ 4,718,592   16384*768*2    = 25,165,824   (aliased)
//   Qf     @ 29,884,416  25,165,824
//   Kf     @ 55,050,240  25,165,824
//   Vt     @ 80,216,064  25,165,824  ([h][b][d][n])
// ---------------------------------------------------------------------------
extern "C" void kernel_launch(void* const* d_in, const int* in_sizes, int n_in,
                              void* d_out, int out_size, void* d_ws,
                              size_t ws_size, hipStream_t stream) {
  const float* z = (const float*)d_in[0];
  const float* Uqkv = (const float*)d_in[1];
  const float* Umsa = (const float*)d_in[2];

  char* ws = (char*)d_ws;
  _Float16* Ut_qkv = (_Float16*)(ws);
  _Float16* Ut_msa = (_Float16*)(ws + 3538944);
  _Float16* zh = (_Float16*)(ws + 4718592);
  _Float16* Of = zh;  // aliased (zh dead before attn writes Of)
  _Float16* Qf = (_Float16*)(ws + 29884416);
  _Float16* Kf = (_Float16*)(ws + 55050240);
  _Float16* Vt = (_Float16*)(ws + 80216064);

  prep_kernel<<<dim3(15360), 256, 0, stream>>>(z, Uqkv, Umsa, zh, Ut_qkv,
                                               Ut_msa);
  qkv_gemm_kernel<<<dim3(128, 18), 256, 0, stream>>>(zh, Ut_qkv, Qf, Kf, Vt);
  attn_kernel<<<dim3(1536, 1), 256, 0, stream>>>(Qf, Kf, Vt, Of);
  out_gemm_kernel<<<dim3(128, 6), 256, 0, stream>>>(Of, Ut_msa,
                                                    (float*)d_out);
}